// Round 8
// baseline (86.588 us; speedup 1.0000x reference)
//
#include <hip/hip_runtime.h>
#include <hip/hip_bf16.h>

namespace {

constexpr int T_DIM = 16384;   // number of tiles
constexpr int TPW   = 4;       // tiles per wave -> 16/block -> 1024 blocks
constexpr int LDST  = 18;      // padded LDS stride (conflict-free transpose)

typedef __attribute__((ext_vector_type(8))) short bf16x8;
typedef __attribute__((ext_vector_type(4))) float f32x4;

__device__ inline short f2bf(float f) {
    union { __hip_bfloat16 h; short s; } u;
    u.h = __float2bfloat16(f);
    return u.s;
}

__device__ inline bf16x8 cvt8(f32x4 a, f32x4 b) {
    bf16x8 r;
    r[0] = f2bf(a[0]); r[1] = f2bf(a[1]); r[2] = f2bf(a[2]); r[3] = f2bf(a[3]);
    r[4] = f2bf(b[0]); r[5] = f2bf(b[1]); r[6] = f2bf(b[2]); r[7] = f2bf(b[3]);
    return r;
}

} // namespace

// Wave-private streaming, W1 as MFMA *A*-operand (rows = j):
//  - each wave owns TPW whole tiles; W1 global->reg->MFMA, each element
//    loaded & converted exactly ONCE (R7 converted 4x redundantly).
//  - x held in registers as B-frags (all 128 b; loop-invariant, 64 VGPR).
//  - D layout: j = jf*16 + 4*l4 + reg (4 j IN-LANE), b = bf*16 + l15 ->
//    stage-2 fold is in-lane + 2 shfls per bf (16/tile vs R7's 128).
//  - ZERO barriers in the main loop; depth-1 jf-pipeline (2 named buffers,
//    rule #20) keeps ~6 VMEM in flight per wave continuously.
//  - y transposed via small padded LDS at the end (one __syncthreads),
//    stores are 32B/thread, sector-perfect.
__global__ __launch_bounds__(256, 2) void fgbn_kernel(
    const float* __restrict__ x,
    const float* __restrict__ W1,
    const float* __restrict__ b1,
    const float* __restrict__ W2,
    const float* __restrict__ b2,
    float* __restrict__ out)
{
    __shared__ float y_lds[128 * LDST];   // [b][tloc], padded -> 9 KB

    const int tid    = threadIdx.x;
    const int lane   = tid & 63;
    const int wave   = tid >> 6;
    const int l15    = lane & 15;
    const int l4     = lane >> 4;
    const int tblock = blockIdx.x * (4 * TPW);
    const int t0w    = tblock + wave * TPW;

    // x as B-fragments: B[k=8*l4+e][col=l15] for b = bf*16+l15, k' = ks*32+k.
    bf16x8 xb[8][2];
    #pragma unroll
    for (int bf = 0; bf < 8; ++bf) {
        #pragma unroll
        for (int ks = 0; ks < 2; ++ks) {
            const float* src = x + (bf * 16 + l15) * 64 + ks * 32 + l4 * 8;
            xb[bf][ks] = cvt8(*reinterpret_cast<const f32x4*>(src),
                              *reinterpret_cast<const f32x4*>(src + 4));
        }
    }

    // One jf-group = 16 j-rows x 64 k of W1 (+ its b1/W2 quads).
    // A-frag: row=l15 (j-local), k=8*l4+e; per lane 8 contiguous f32 per ks.
    auto load_grp = [&](int t, int jf, f32x4& w0, f32x4& w1, f32x4& w2_,
                        f32x4& w3, f32x4& bv, f32x4& wv) {
        const float* base = W1 + (size_t)t * 4096 + (jf * 16 + l15) * 64 + l4 * 8;
        w0  = *reinterpret_cast<const f32x4*>(base);
        w1  = *reinterpret_cast<const f32x4*>(base + 4);
        w2_ = *reinterpret_cast<const f32x4*>(base + 32);
        w3  = *reinterpret_cast<const f32x4*>(base + 36);
        bv  = *reinterpret_cast<const f32x4*>(b1 + t * 64 + jf * 16 + l4 * 4);
        wv  = *reinterpret_cast<const f32x4*>(W2 + t * 64 + jf * 16 + l4 * 4);
    };

    float s[8];
    // Compute one jf-group: 16 MFMA + in-lane relu-dot fold into s[bf].
    auto step = [&](f32x4& w0, f32x4& w1, f32x4& w2_, f32x4& w3,
                    f32x4& bv, f32x4& wv) {
        const bf16x8 a0 = cvt8(w0, w1);    // ks=0
        const bf16x8 a1 = cvt8(w2_, w3);   // ks=1
        #pragma unroll
        for (int bf = 0; bf < 8; ++bf) {
            f32x4 acc = (f32x4){0.f, 0.f, 0.f, 0.f};
            acc = __builtin_amdgcn_mfma_f32_16x16x32_bf16(a0, xb[bf][0], acc, 0, 0, 0);
            acc = __builtin_amdgcn_mfma_f32_16x16x32_bf16(a1, xb[bf][1], acc, 0, 0, 0);
            #pragma unroll
            for (int r = 0; r < 4; ++r) {
                const float p = fmaxf(acc[r] + bv[r], 0.f);
                s[bf] = fmaf(p, wv[r], s[bf]);
            }
        }
    };

    // Two named pipeline buffers (depth-1 lookahead; parity fixed per jf).
    f32x4 A0a, A0b, A0c, A0d, B0, V0;   // even jf
    f32x4 A1a, A1b, A1c, A1d, B1, V1;   // odd jf

    load_grp(t0w, 0, A0a, A0b, A0c, A0d, B0, V0);

    for (int i = 0; i < TPW; ++i) {
        const int t = t0w + i;
        const float b2t = b2[t];
        #pragma unroll
        for (int bf = 0; bf < 8; ++bf) s[bf] = 0.f;

        load_grp(t, 1, A1a, A1b, A1c, A1d, B1, V1);          // prefetch jf1
        step(A0a, A0b, A0c, A0d, B0, V0);                    // compute jf0
        load_grp(t, 2, A0a, A0b, A0c, A0d, B0, V0);          // prefetch jf2
        step(A1a, A1b, A1c, A1d, B1, V1);                    // compute jf1
        load_grp(t, 3, A1a, A1b, A1c, A1d, B1, V1);          // prefetch jf3
        step(A0a, A0b, A0c, A0d, B0, V0);                    // compute jf2
        if (i + 1 < TPW)
            load_grp(t + 1, 0, A0a, A0b, A0c, A0d, B0, V0);  // prefetch next tile
        step(A1a, A1b, A1c, A1d, B1, V1);                    // compute jf3

        // Cross-l4 reduction (j-quadrants): 2 shfls per bf; then y -> LDS.
        const int tloc = wave * TPW + i;
        #pragma unroll
        for (int bf = 0; bf < 8; ++bf) {
            float v = s[bf];
            v += __shfl_xor(v, 16);
            v += __shfl_xor(v, 32);
            if (l4 == 0)
                y_lds[(bf * 16 + l15) * LDST + tloc] = 2.f * (v + b2t);
        }
    }

    __syncthreads();   // the only block-wide barrier

    // Epilogue: thread tid -> row b = tid>>1, half h = tid&1: 32B contiguous
    // per thread; even/odd pairs fill 64B lines (sector-perfect).
    {
        const int b = tid >> 1, h = tid & 1;
        float v[8];
        #pragma unroll
        for (int k = 0; k < 8; ++k) v[k] = y_lds[b * LDST + h * 8 + k];
        float* dst = out + (size_t)b * T_DIM + tblock + h * 8;
        *reinterpret_cast<f32x4*>(dst)     = (f32x4){v[0], v[1], v[2], v[3]};
        *reinterpret_cast<f32x4*>(dst + 4) = (f32x4){v[4], v[5], v[6], v[7]};
    }
}

extern "C" void kernel_launch(void* const* d_in, const int* in_sizes, int n_in,
                              void* d_out, int out_size, void* d_ws, size_t ws_size,
                              hipStream_t stream) {
    const float* x  = (const float*)d_in[0];
    const float* W1 = (const float*)d_in[1];
    const float* b1 = (const float*)d_in[2];
    const float* W2 = (const float*)d_in[3];
    const float* b2 = (const float*)d_in[4];
    float* out = (float*)d_out;

    dim3 grid(T_DIM / (4 * TPW));   // 1024 blocks
    dim3 block(256);
    hipLaunchKernelGGL(fgbn_kernel, grid, block, 0, stream,
                       x, W1, b1, W2, b2, out);
}